// Round 4
// baseline (350.636 us; speedup 1.0000x reference)
//
#include <hip/hip_runtime.h>
#include <hip/hip_bf16.h>
#include <stdint.h>

#define M_TOT 8192
#define N_TOT 4096
#define K_TOT 4096
#define BM 256
#define BN 256
#define BK 64
#define NT (K_TOT / BK)   // 64 K-tiles

typedef short s16x8 __attribute__((ext_vector_type(8)));
typedef float f32x4 __attribute__((ext_vector_type(4)));

// fp32 -> bf16 round-to-nearest-even
__device__ __forceinline__ short f2bf(float f) {
    unsigned int u = __float_as_uint(f);
    u = (u + 0x7fffu + ((u >> 16) & 1u)) >> 16;
    return (short)u;
}

__device__ __forceinline__ void async_copy16(const void* g, void* l) {
    __builtin_amdgcn_global_load_lds(
        (const __attribute__((address_space(1))) void*)g,
        (__attribute__((address_space(3))) void*)l, 16, 0, 0);
}

// ---------------- pass 1a: x fp32 -> bf16 ----------------
__global__ __launch_bounds__(256)
void cvt_x(const float* __restrict__ x, short* __restrict__ xbf, int n8) {
    const int idx = blockIdx.x * blockDim.x + threadIdx.x;
    const int stride = gridDim.x * blockDim.x;
    for (int i = idx; i < n8; i += stride) {
        const float4 f0 = ((const float4*)x)[(size_t)i * 2];
        const float4 f1 = ((const float4*)x)[(size_t)i * 2 + 1];
        s16x8 v;
        v[0] = f2bf(f0.x); v[1] = f2bf(f0.y); v[2] = f2bf(f0.z); v[3] = f2bf(f0.w);
        v[4] = f2bf(f1.x); v[5] = f2bf(f1.y); v[6] = f2bf(f1.z); v[7] = f2bf(f1.w);
        ((s16x8*)xbf)[i] = v;
    }
}

// ---------------- pass 1b: int4 -> bf16 W^T [OUT][IN] ----------------
__global__ __launch_bounds__(256)
void dequant_w(const int* __restrict__ qw, const float* __restrict__ scales,
               const float* __restrict__ zeros, short* __restrict__ wt) {
    const int o = blockIdx.x * 256 + threadIdx.x;
    const int r0 = blockIdx.y * 32;
    const float c0 = scales[o];
    const float c1 = -rintf(zeros[o] / c0) * c0;
    #pragma unroll
    for (int j = 0; j < 8; ++j) {
        s16x8 v;
        #pragma unroll
        for (int i = 0; i < 4; ++i) {
            const int q = qw[(size_t)(r0 + j * 4 + i) * N_TOT + o];
            v[2 * i]     = f2bf(fmaf((float)(q & 15), c0, c1));
            v[2 * i + 1] = f2bf(fmaf((float)((q >> 4) & 15), c0, c1));
        }
        *(s16x8*)&wt[(size_t)o * K_TOT + r0 * 2 + j * 8] = v;
    }
}

// ---------------- pass 2: 256^2 8-phase bf16 GEMM ----------------
__global__ __launch_bounds__(512, 2)
void gemm_bf16(const short* __restrict__ xbf, const short* __restrict__ wt,
               const float* __restrict__ bias, float* __restrict__ out) {
    __shared__ short As[2][BM * BK];   // 2 x 32 KiB
    __shared__ short Bs[2][BN * BK];   // 2 x 32 KiB  (W^T rows = output cols)

    const int tid  = threadIdx.x;
    const int bid  = blockIdx.x;
    // XCD-aware bijective swizzle (512 % 8 == 0)
    const int sw   = (bid & 7) * 64 + (bid >> 3);
    const int n0   = (sw >> 5) * BN;   // 16 n-blocks
    const int m0   = (sw & 31) * BM;   // 32 m-blocks
    const int lane = tid & 63;
    const int wid  = tid >> 6;         // 0..7
    const int wr   = wid >> 2;         // 0..1 (M)
    const int wc   = wid & 3;          // 0..3 (N)
    const int lrow = lane & 15;
    const int lk   = lane >> 4;
    const int gb0  = tid & 448;        // wave-aligned base of tid

    f32x4 acc[8][4] = {};
    s16x8 afr[4][2], bfr[2][2];

    // stage one A half-chunk: rows {r : bit6(r)==half}, 2 loads/thread.
    // LDS dest wave-uniform base (HW adds lane*16); source pre-swizzled (rule 21).
    auto stageA = [&](int bb, int kt, int half) {
        const int k0 = (kt & (NT - 1)) * BK;
        #pragma unroll
        for (int j = 0; j < 2; ++j) {
            const int g  = j * 512 + tid;
            const int R  = ((g >> 3) & 63) + ((g >> 9) & 1) * 128 + half * 64;
            const int c  = g & 7;
            const int gb = j * 512 + gb0;
            const int Rb = ((gb >> 3) & 63) + ((gb >> 9) & 1) * 128 + half * 64;
            async_copy16(xbf + (size_t)(m0 + R) * K_TOT + k0 + ((c ^ (R & 7)) << 3),
                         &As[bb][Rb * 64]);
        }
    };
    // stage one B half-chunk: rows {r : bit5(r)==half}
    auto stageB = [&](int bb, int kt, int half) {
        const int k0 = (kt & (NT - 1)) * BK;
        #pragma unroll
        for (int j = 0; j < 2; ++j) {
            const int g  = j * 512 + tid;
            const int R  = ((g >> 3) & 31) + ((g >> 8) & 3) * 64 + half * 32;
            const int c  = g & 7;
            const int gb = j * 512 + gb0;
            const int Rb = ((gb >> 3) & 31) + ((gb >> 8) & 3) * 64 + half * 32;
            async_copy16(wt + (size_t)(n0 + R) * K_TOT + k0 + ((c ^ (R & 7)) << 3),
                         &Bs[bb][Rb * 64]);
        }
    };

#define READ_A(BUF, MH)                                                          \
    _Pragma("unroll")                                                            \
    for (int mi = 0; mi < 4; ++mi) {                                             \
        const int row = wr * 128 + (MH) * 64 + mi * 16 + lrow;                   \
        _Pragma("unroll")                                                        \
        for (int ks = 0; ks < 2; ++ks) {                                         \
            const int gran = ks * 4 + lk;                                        \
            afr[mi][ks] = *(const s16x8*)&As[BUF][row * 64 + ((gran ^ (row & 7)) << 3)]; \
        }                                                                        \
    }

#define READ_B(BUF, NH)                                                          \
    _Pragma("unroll")                                                            \
    for (int ni = 0; ni < 2; ++ni) {                                             \
        const int row = wc * 64 + (NH) * 32 + ni * 16 + lrow;                    \
        _Pragma("unroll")                                                        \
        for (int ks = 0; ks < 2; ++ks) {                                         \
            const int gran = ks * 4 + lk;                                        \
            bfr[ni][ks] = *(const s16x8*)&Bs[BUF][row * 64 + ((gran ^ (row & 7)) << 3)]; \
        }                                                                        \
    }

#define PHASE(BUF, MH, NH, RA, STAGE_STMT, VM)                                   \
    {                                                                            \
        if (RA) { READ_A(BUF, MH); }                                             \
        READ_B(BUF, NH);                                                         \
        STAGE_STMT;                                                              \
        if (VM) asm volatile("s_waitcnt vmcnt(4)" ::: "memory");                 \
        __builtin_amdgcn_s_barrier();                                            \
        asm volatile("s_waitcnt lgkmcnt(0)" ::: "memory");                       \
        __builtin_amdgcn_s_setprio(1);                                           \
        _Pragma("unroll")                                                        \
        for (int ks = 0; ks < 2; ++ks)                                           \
            _Pragma("unroll")                                                    \
            for (int mi = 0; mi < 4; ++mi)                                       \
                _Pragma("unroll")                                                \
                for (int ni = 0; ni < 2; ++ni)                                   \
                    acc[(MH) * 4 + mi][(NH) * 2 + ni] =                          \
                        __builtin_amdgcn_mfma_f32_16x16x32_bf16(                 \
                            afr[mi][ks], bfr[ni][ks],                            \
                            acc[(MH) * 4 + mi][(NH) * 2 + ni], 0, 0, 0);         \
        __builtin_amdgcn_s_setprio(0);                                           \
        __builtin_amdgcn_s_barrier();                                            \
    }

    // prologue: tile0 (all 4 chunks) + tile1 (A0,B0) = 12 loads/thread
    stageA(0, 0, 0); stageB(0, 0, 0);
    stageA(0, 0, 1); stageB(0, 0, 1);
    stageA(1, 1, 0); stageB(1, 1, 0);
    asm volatile("s_waitcnt vmcnt(4)" ::: "memory");   // tile0 fully landed
    __builtin_amdgcn_s_barrier();

    for (int i = 0; i < NT / 2; ++i) {
        const int t = 2 * i;
        PHASE(0, 0, 0, 1, stageA(1, t + 1, 1), 0);   // lands by P3's wait, read P6
        PHASE(0, 0, 1, 0, stageB(1, t + 1, 1), 0);   // read P5/P7
        PHASE(0, 1, 0, 1, stageA(0, t + 2, 0), 0);   // read next-iter P0
        PHASE(0, 1, 1, 0, stageB(0, t + 2, 0), 1);   // vmcnt(4): tile t+1 complete
        PHASE(1, 0, 0, 1, stageA(0, t + 2, 1), 0);
        PHASE(1, 0, 1, 0, stageB(0, t + 2, 1), 0);
        PHASE(1, 1, 0, 1, stageA(1, t + 3, 0), 0);
        PHASE(1, 1, 1, 0, stageB(1, t + 3, 0), 1);   // vmcnt(4): tile t+2 complete
    }
    asm volatile("s_waitcnt vmcnt(0)" ::: "memory");   // drain wrapped strays

    // epilogue: C/D layout col = lane&15, row = (lane>>4)*4 + j
    #pragma unroll
    for (int mi8 = 0; mi8 < 8; ++mi8) {
        const int rg = m0 + wr * 128 + mi8 * 16 + lk * 4;
        #pragma unroll
        for (int ni4 = 0; ni4 < 4; ++ni4) {
            const int cg = n0 + wc * 64 + ni4 * 16 + lrow;
            const float bs = bias[cg];
            #pragma unroll
            for (int j = 0; j < 4; ++j)
                out[(size_t)(rg + j) * N_TOT + cg] = acc[mi8][ni4][j] + bs;
        }
    }
#undef PHASE
#undef READ_A
#undef READ_B
}

// ---------------- fallback: fused kernel (small ws) ----------------
__global__ __launch_bounds__(256, 2)
void qlin_fused(const float* __restrict__ x,
                const int* __restrict__ qw,
                const float* __restrict__ scales,
                const float* __restrict__ zeros,
                const float* __restrict__ bias,
                float* __restrict__ out) {
    __shared__ short As[128 * 64];
    __shared__ short Bs[128 * 64];

    const int tid = threadIdx.x;
    const int n0 = blockIdx.x * 128;
    const int m0 = blockIdx.y * 128;

    const int a_kg   = tid & 7;
    const int a_row0 = tid >> 3;
    const int b_oloc = tid & 127;
    const int b_rg0  = tid >> 7;

    const int ocol = n0 + b_oloc;
    const float c0 = scales[ocol];
    const float c1 = -rintf(zeros[ocol] / c0) * c0;

    const int lane = tid & 63;
    const int wv   = tid >> 6;
    const int wr   = wv >> 1;
    const int wc   = wv & 1;
    const int lrow = lane & 15;
    const int lk   = lane >> 4;

    f32x4 acc[4][4] = {};

    for (int kt = 0; kt < K_TOT / 64; ++kt) {
        const int k0 = kt * 64;
        {
            const float* srcb = x + (size_t)(m0)*K_TOT + k0 + a_kg * 8;
            #pragma unroll
            for (int i = 0; i < 4; ++i) {
                const int row = a_row0 + 32 * i;
                const float4 f0 = *(const float4*)(srcb + (size_t)row * K_TOT);
                const float4 f1 = *(const float4*)(srcb + (size_t)row * K_TOT + 4);
                s16x8 v;
                v[0] = f2bf(f0.x); v[1] = f2bf(f0.y); v[2] = f2bf(f0.z); v[3] = f2bf(f0.w);
                v[4] = f2bf(f1.x); v[5] = f2bf(f1.y); v[6] = f2bf(f1.z); v[7] = f2bf(f1.w);
                *(s16x8*)&As[row * 64 + ((a_kg ^ (row & 7)) << 3)] = v;
            }
        }
        {
            const int rbase = k0 >> 1;
            #pragma unroll
            for (int i = 0; i < 4; ++i) {
                const int rg = b_rg0 + 2 * i;
                const int* qp = qw + (size_t)(rbase + rg * 4) * N_TOT + ocol;
                s16x8 v;
                #pragma unroll
                for (int rr = 0; rr < 4; ++rr) {
                    const int q = qp[(size_t)rr * N_TOT];
                    v[2 * rr]     = f2bf(fmaf((float)(q & 15), c0, c1));
                    v[2 * rr + 1] = f2bf(fmaf((float)((q >> 4) & 15), c0, c1));
                }
                *(s16x8*)&Bs[b_oloc * 64 + ((rg ^ (b_oloc & 7)) << 3)] = v;
            }
        }
        __syncthreads();
        #pragma unroll
        for (int ks = 0; ks < 2; ++ks) {
            const int slot = ks * 4 + lk;
            s16x8 a[4], b[4];
            #pragma unroll
            for (int mi = 0; mi < 4; ++mi) {
                const int row = wr * 64 + mi * 16 + lrow;
                a[mi] = *(const s16x8*)&As[row * 64 + ((slot ^ (row & 7)) << 3)];
            }
            #pragma unroll
            for (int ni = 0; ni < 4; ++ni) {
                const int row = wc * 64 + ni * 16 + lrow;
                b[ni] = *(const s16x8*)&Bs[row * 64 + ((slot ^ (row & 7)) << 3)];
            }
            #pragma unroll
            for (int mi = 0; mi < 4; ++mi)
                #pragma unroll
                for (int ni = 0; ni < 4; ++ni)
                    acc[mi][ni] = __builtin_amdgcn_mfma_f32_16x16x32_bf16(
                        a[mi], b[ni], acc[mi][ni], 0, 0, 0);
        }
        __syncthreads();
    }

    #pragma unroll
    for (int mi = 0; mi < 4; ++mi) {
        const int rg = m0 + wr * 64 + mi * 16 + lk * 4;
        #pragma unroll
        for (int ni = 0; ni < 4; ++ni) {
            const int cg = n0 + wc * 64 + ni * 16 + lrow;
            const float bs = bias[cg];
            #pragma unroll
            for (int j = 0; j < 4; ++j)
                out[(size_t)(rg + j) * N_TOT + cg] = acc[mi][ni][j] + bs;
        }
    }
}

extern "C" void kernel_launch(void* const* d_in, const int* in_sizes, int n_in,
                              void* d_out, int out_size, void* d_ws, size_t ws_size,
                              hipStream_t stream) {
    const float* x      = (const float*)d_in[0];
    const int*   qw     = (const int*)d_in[1];
    const float* scales = (const float*)d_in[2];
    const float* zeros  = (const float*)d_in[3];
    const float* bias   = (const float*)d_in[4];
    float* out = (float*)d_out;

    const size_t XBF_BYTES = (size_t)M_TOT * K_TOT * 2;
    const size_t WT_BYTES  = (size_t)N_TOT * K_TOT * 2;

    if (ws_size >= XBF_BYTES + WT_BYTES) {
        short* xbf = (short*)d_ws;
        short* wt  = (short*)((char*)d_ws + XBF_BYTES);

        hipLaunchKernelGGL(cvt_x, dim3(2048), dim3(256), 0, stream,
                           x, xbf, (int)((size_t)M_TOT * K_TOT / 8));
        hipLaunchKernelGGL(dequant_w, dim3(N_TOT / 256, K_TOT / 64), dim3(256), 0, stream,
                           qw, scales, zeros, wt);
        hipLaunchKernelGGL(gemm_bf16, dim3((M_TOT / BM) * (N_TOT / BN)), dim3(512), 0, stream,
                           xbf, wt, bias, out);
    } else {
        hipLaunchKernelGGL(qlin_fused, dim3(N_TOT / 128, M_TOT / 128), dim3(256), 0, stream,
                           x, qw, scales, zeros, bias, out);
    }
}